// Round 1
// baseline (411.297 us; speedup 1.0000x reference)
//
#include <hip/hip_runtime.h>
#include <cstddef>

// Problem constants (fixed by setup_inputs)
#define B_  4
#define L_  1024
#define H_  8
#define DK_ 32
#define DV_ 32
#define BH_ 32            // B_*H_
#define HD_ 256           // H_*DK_

#define INV_T 0.17677669529663687f  // 1/sqrt(32)

// ---------------------------------------------------------------------------
// Kernel 0: transpose q[b, j, h*32+d] -> qT[bh][d][j]  (so j is contiguous)
// grid 128 = bh(32) x jt(4), 256 threads
// ---------------------------------------------------------------------------
__global__ __launch_bounds__(256) void transpose_q(
    const float* __restrict__ q, float* __restrict__ qT)
{
    const int bh  = blockIdx.x >> 2;
    const int jt  = blockIdx.x & 3;
    const int b   = bh >> 3, h = bh & 7;
    const int tid = threadIdx.x;

    __shared__ float t_s[256][33];

    const float* qb = q + (size_t)b * L_ * HD_ + h * DK_;
    #pragma unroll
    for (int rep = 0; rep < 8; ++rep) {
        const int f = rep * 1024 + tid * 4;
        const int j = f >> 5, d = f & 31;
        float4 val = *reinterpret_cast<const float4*>(qb + (size_t)(jt * 256 + j) * HD_ + d);
        t_s[j][d + 0] = val.x; t_s[j][d + 1] = val.y;
        t_s[j][d + 2] = val.z; t_s[j][d + 3] = val.w;
    }
    __syncthreads();
    float* qo = qT + (size_t)bh * (DK_ * L_) + jt * 256;
    #pragma unroll
    for (int d = 0; d < 32; ++d)
        qo[(size_t)d * L_ + tid] = t_s[tid][d];
}

// ---------------------------------------------------------------------------
// Kernel 1: scores. grid 1024 = ig(256) x half(2) x jhalf(2).
// Block: 4 i's x 16 bh x 512 j's. 256 thr = 4 waves; wave w -> bh w*4..w*4+3.
// k is wave-uniform -> scalar loads (SGPR broadcast), no k LDS.
// Writes u = exp(score/T) + per-row partial sums (per jhalf).
// ---------------------------------------------------------------------------
__global__ __launch_bounds__(256) void score_kernel(
    const float* __restrict__ qT,
    const float* __restrict__ k,
    const float* __restrict__ a_k,
    float* __restrict__ attn_u,
    float* __restrict__ sums)   // [2][BH_][L_] partials
{
    const int bidx  = blockIdx.x;
    const int jhalf = bidx & 1;
    const int half  = (bidx >> 1) & 1;
    const int ig    = bidx >> 2;
    const int i0    = ig * 4;
    const int bh0   = half * 16;
    const int tid   = threadIdx.x;
    const int w     = __builtin_amdgcn_readfirstlane(tid >> 6);  // force wave-uniform
    const int lane  = tid & 63;

    __shared__ float a_s[4][64][36];   // [ii][jj][d] pad 36 (b128 conflict-free)

    float rs[4][4] = {{0.f}};          // [bhl][ii] row-sum partials

    for (int jt = jhalf * 8; jt < jhalf * 8 + 8; ++jt) {
        const int j0 = jt * 64;
        __syncthreads();
        #pragma unroll
        for (int rep = 0; rep < 8; ++rep) {
            const int f  = rep * 1024 + tid * 4;
            const int ii = f >> 11, jj = (f >> 5) & 63, d = f & 31;
            float4 val = *reinterpret_cast<const float4*>(
                a_k + (size_t)(i0 + ii) * (L_ * DK_) + (size_t)(j0 + jj) * DK_ + d);
            *reinterpret_cast<float4*>(&a_s[ii][jj][d]) = val;
        }
        __syncthreads();

        float s[4][4];
        #pragma unroll
        for (int bhl = 0; bhl < 4; ++bhl)
            #pragma unroll
            for (int ii = 0; ii < 4; ++ii) s[bhl][ii] = 0.f;

        #pragma unroll 2
        for (int d4 = 0; d4 < 8; ++d4) {
            float4 av[4];
            #pragma unroll
            for (int ii = 0; ii < 4; ++ii)
                av[ii] = *reinterpret_cast<const float4*>(&a_s[ii][lane][d4 * 4]);
            #pragma unroll
            for (int bhl = 0; bhl < 4; ++bhl) {
                const int bh = bh0 + w * 4 + bhl;      // wave-uniform
                const int b  = bh >> 3, h = bh & 7;
                const float* qp = qT + (size_t)bh * (DK_ * L_) + (size_t)(d4 * 4) * L_ + j0 + lane;
                const float q0 = qp[0];
                const float q1 = qp[L_];
                const float q2 = qp[2 * L_];
                const float q3 = qp[3 * L_];
                const float* kp = k + (size_t)b * L_ * HD_ + (size_t)i0 * HD_ + h * DK_ + d4 * 4;
                #pragma unroll
                for (int ii = 0; ii < 4; ++ii) {
                    float4 kv = *reinterpret_cast<const float4*>(kp + ii * HD_);  // s_load
                    s[bhl][ii] = fmaf(kv.x * av[ii].x, q0, s[bhl][ii]);
                    s[bhl][ii] = fmaf(kv.y * av[ii].y, q1, s[bhl][ii]);
                    s[bhl][ii] = fmaf(kv.z * av[ii].z, q2, s[bhl][ii]);
                    s[bhl][ii] = fmaf(kv.w * av[ii].w, q3, s[bhl][ii]);
                }
            }
        }

        #pragma unroll
        for (int bhl = 0; bhl < 4; ++bhl) {
            const int bh = bh0 + w * 4 + bhl;
            #pragma unroll
            for (int ii = 0; ii < 4; ++ii) {
                const float u = __expf(s[bhl][ii] * INV_T);
                rs[bhl][ii] += u;
                attn_u[((size_t)bh * L_ + (i0 + ii)) * L_ + j0 + lane] = u;
            }
        }
    }

    #pragma unroll
    for (int bhl = 0; bhl < 4; ++bhl) {
        #pragma unroll
        for (int ii = 0; ii < 4; ++ii) {
            float vsum = rs[bhl][ii];
            #pragma unroll
            for (int off = 32; off > 0; off >>= 1) vsum += __shfl_xor(vsum, off);
            if (lane == 0)
                sums[((size_t)jhalf * BH_ + bh0 + w * 4 + bhl) * L_ + i0 + ii] = vsum;
        }
    }
}

// ---------------------------------------------------------------------------
// Kernel 2: normalize + PV. grid 2048 = bh(32) x ic(64: 16 i-rows each).
// 256 thr: r = tid>>4 (row 0..15), t16 = tid&15.
// ---------------------------------------------------------------------------
__global__ __launch_bounds__(256) void pv_kernel(
    const float* __restrict__ v,
    const float* __restrict__ sums,
    float* __restrict__ attn,    // u on entry, p on exit
    float* __restrict__ out)
{
    const int bh  = blockIdx.x >> 6;
    const int ic  = blockIdx.x & 63;
    const int i0  = ic * 16;
    const int b   = bh >> 3, h = bh & 7;
    const int tid = threadIdx.x;
    const int r   = tid >> 4;
    const int t16 = tid & 15;

    __shared__ float v_s[64][36];    // [jj][dv] pad 36
    __shared__ float u_s[16][68];    // pad 68: broadcast reads conflict-free

    const float inv = 1.0f / (sums[(size_t)bh * L_ + i0 + r] +
                              sums[(size_t)(BH_ + bh) * L_ + i0 + r]);
    float* arow = attn + ((size_t)bh * L_ + i0 + r) * L_;

    float a0 = 0.f, a1 = 0.f;

    for (int jt = 0; jt < 16; ++jt) {
        const int j0 = jt * 64;
        __syncthreads();
        {   // stage v tile (64 x 32)
            const int jj = tid >> 2, dv = (tid & 3) * 8;
            const float* vp = v + (size_t)b * L_ * HD_ + (size_t)(j0 + jj) * HD_ + h * DV_ + dv;
            float4 v0 = *reinterpret_cast<const float4*>(vp);
            float4 v1 = *reinterpret_cast<const float4*>(vp + 4);
            *reinterpret_cast<float4*>(&v_s[jj][dv])     = v0;
            *reinterpret_cast<float4*>(&v_s[jj][dv + 4]) = v1;
        }
        {   // stage u tile normalized; write p back
            float4 u0 = *reinterpret_cast<const float4*>(arow + j0 + t16 * 4);
            u0.x *= inv; u0.y *= inv; u0.z *= inv; u0.w *= inv;
            *reinterpret_cast<float4*>(&u_s[r][t16 * 4]) = u0;
            *reinterpret_cast<float4*>(arow + j0 + t16 * 4) = u0;
        }
        __syncthreads();
        // acc[dv pair] += p[r][jj] * v[jj][dv]
        #pragma unroll
        for (int jj = 0; jj < 64; ++jj) {
            const float ub = u_s[r][jj];                          // broadcast
            const float2 vv = *reinterpret_cast<const float2*>(&v_s[jj][t16 * 2]);
            a0 = fmaf(ub, vv.x, a0);
            a1 = fmaf(ub, vv.y, a1);
        }
    }
    *reinterpret_cast<float2*>(out + ((size_t)bh * L_ + i0 + r) * DV_ + t16 * 2)
        = make_float2(a0, a1);
}

extern "C" void kernel_launch(void* const* d_in, const int* in_sizes, int n_in,
                              void* d_out, int out_size, void* d_ws, size_t ws_size,
                              hipStream_t stream) {
    const float* q   = (const float*)d_in[0];
    const float* k   = (const float*)d_in[1];
    const float* v   = (const float*)d_in[2];
    const float* a_k = (const float*)d_in[3];

    float* out  = (float*)d_out;
    float* attn = out + (size_t)BH_ * L_ * DV_;   // out first, attn second

    float* ws   = (float*)d_ws;
    float* sums = ws;                        // 2*32*1024 floats = 256 KB
    float* qT   = ws + 2 * BH_ * L_;         // 4 MB

    transpose_q<<<dim3(128),   dim3(256), 0, stream>>>(q, qT);
    score_kernel<<<dim3(1024), dim3(256), 0, stream>>>(qT, k, a_k, attn, sums);
    pv_kernel<<<dim3(2048),    dim3(256), 0, stream>>>(v, sums, attn, out);
}